// Round 3
// baseline (127.591 us; speedup 1.0000x reference)
//
#include <hip/hip_runtime.h>
#include <hip/hip_bf16.h>
#include <math.h>

#define N 4096
#define D 256
#define SCALEF 10.0f
#define EPSF 1e-5f
#define MARGIN_INTRA 40.0f
#define MARGIN_INTER 6.0f
// reference excludes sorted_intra[0:4] = diagonal + top-3 non-diag, sorted_inter[0:6]
#define LI 3
#define LX 6
#define NCHUNK 16   // j-chunks of 256
#define NSTRIP 64   // i-strips of 64 -> 1024 blocks = 4 blocks/CU (grid was the
                    // occupancy limiter at 512 blocks: 18% occ, 24us dead time)
#define PPARTS (NCHUNK * 2)  // partial per (chunk, wr) -- unchanged by NSTRIP

#define LOG2EF 1.44269504f
#define LN2F 0.69314718f

typedef unsigned short ushort_t;
typedef __attribute__((ext_vector_type(8))) short short8;
typedef __attribute__((ext_vector_type(4))) float floatx4;

__device__ __forceinline__ ushort_t f2bf(float x) {
    __hip_bfloat16 h = __float2bfloat16(x);
    return *reinterpret_cast<ushort_t*>(&h);
}
__device__ __forceinline__ float bf2f(ushort_t u) {
    __hip_bfloat16 h = *reinterpret_cast<__hip_bfloat16*>(&u);
    return __bfloat162float(h);
}

__device__ __forceinline__ float fast_exp2(float x) {
#if __has_builtin(__builtin_amdgcn_exp2f)
    return __builtin_amdgcn_exp2f(x);
#else
    return exp2f(x);
#endif
}

// Insert v into descending-sorted list t[0..L-1], keep top L.
// t0' = max(t0,v); tq' = med3(t[q-1], t[q], v)  -> L ops, depth-1 chain.
template <int L>
__device__ __forceinline__ void insert_desc(float (&t)[L], float v) {
    float top = fmaxf(t[0], v);
#pragma unroll
    for (int q = L - 1; q >= 1; --q)
        t[q] = __builtin_amdgcn_fmed3f(t[q - 1], t[q], v);
    t[0] = top;
}

// ---------------- Kernel 1: per-row sq, R, bf16 hi/lo split ----------------
__global__ __launch_bounds__(64) void prep_kernel(const float* __restrict__ F,
                                                  ushort_t* __restrict__ Fhi,
                                                  ushort_t* __restrict__ Flo,
                                                  float* __restrict__ sq,
                                                  float* __restrict__ Rrow,
                                                  float* __restrict__ out) {
    int row = blockIdx.x;
    int lane = threadIdx.x;
    if (row == 0 && lane == 0) out[0] = 0.0f;  // for merge_kernel's atomicAdd
    float4 v = ((const float4*)(F + (size_t)row * D))[lane];
    ushort4 h, l;
    h.x = f2bf(v.x); l.x = f2bf(v.x - bf2f(h.x));
    h.y = f2bf(v.y); l.y = f2bf(v.y - bf2f(h.y));
    h.z = f2bf(v.z); l.z = f2bf(v.z - bf2f(h.z));
    h.w = f2bf(v.w); l.w = f2bf(v.w - bf2f(h.w));
    ((ushort4*)(Fhi + (size_t)row * D))[lane] = h;
    ((ushort4*)(Flo + (size_t)row * D))[lane] = l;
    float s = v.x * v.x + v.y * v.y + v.z * v.z + v.w * v.w;
#pragma unroll
    for (int off = 32; off > 0; off >>= 1) s += __shfl_down(s, off, 64);
    if (lane == 0) {
        sq[row] = s;
        Rrow[row] = -SCALEF * sqrtf(2.0f * s);  // per-row exp reference shift
    }
}

// ---------------- Kernel 2: fused GEMM + online masked-topk-LSE ----------------
// Block: 64 rows (i) x 256 cols (j), 256 threads. Gram tile TRANSPOSED:
// MFMA A-operand <- j-features (128-row LDS region), B-operand <- i-features
// (64-row region); each lane's acc holds 2 i-rows (ni) x 16 j-cols per mi.
// LDST=40 (80 B): rows 16B-aligned (single ds_{read,write}_b128; LDST=34
// regressed 1.7x from misalignment splits).
#define LDST 40

// Epilogue for one finished 128(j) x (wave-tile) accumulation.
// Keys are base-2: k2 = (x - R)*log2e = fma(d, -SCALE*log2e, -R*log2e);
// exp contribution is one v_exp_f32: exp2(k2) = exp(x - R).
template <bool HD>
__device__ __forceinline__ void epi_tile(
    const floatx4 (&acc)[4][2], int j0, int wr, int quad,
    const float (&si)[2], const float (&nR2)[2], const int (&ci4)[2], const int (&ig)[2],
    const float* __restrict__ sq, const int* __restrict__ camid,
    float (&tI)[2][LI], float (&tX)[2][LX], float (&sIa)[2], float (&sXa)[2]) {
    const float C1 = -SCALEF * LOG2EF;
#pragma unroll
    for (int mi = 0; mi < 4; ++mi) {
        int jg0 = j0 + wr * 64 + mi * 16 + quad * 4;
        float4 sj4 = *(const float4*)(sq + jg0);
        int4 cj4 = *(const int4*)(camid + jg0);
        const float* sjp = (const float*)&sj4;
        const int* cjp = (const int*)&cj4;
#pragma unroll
        for (int ni = 0; ni < 2; ++ni) {
            int dd = jg0 - ig[ni];  // diagonal at r == -dd
            float sie = si[ni] + EPSF;
#pragma unroll
            for (int r = 0; r < 4; ++r) {
                float d2 = sie + sjp[r] - 2.0f * acc[mi][ni][r];
                float d = sqrtf(fmaxf(d2, 1e-12f));
                float k = fmaf(d, C1, nR2[ni]);  // (x - R) * log2e
                float e = fast_exp2(k);
                bool ii = (cjp[r] == ci4[ni]);
                bool okI = HD ? (ii && ((dd + r) != 0)) : ii;
                sIa[ni] += okI ? e : 0.0f;
                sXa[ni] += ii ? 0.0f : e;
                insert_desc<LI>(tI[ni], okI ? k : -INFINITY);
                insert_desc<LX>(tX[ni], ii ? -INFINITY : k);
            }
        }
    }
}

__global__ __launch_bounds__(256, 4) void fused_kernel(
    const ushort_t* __restrict__ Fhi, const ushort_t* __restrict__ Flo,
    const float* __restrict__ sq, const float* __restrict__ Rrow,
    const int* __restrict__ camid,
    float4* __restrict__ partA, float4* __restrict__ partB, float4* __restrict__ partC) {
    // regions: Ahi[128], Alo[128], Bhi[64], Blo[64] rows of LDST shorts = 30720 B
    __shared__ ushort_t lds[(128 + 128 + 64 + 64) * LDST];
    ushort_t* ldsAh = lds;
    ushort_t* ldsAl = lds + 128 * LDST;
    ushort_t* ldsBh = lds + 256 * LDST;
    ushort_t* ldsBl = lds + 320 * LDST;

    int tid = threadIdx.x;
    int wave = tid >> 6, lane = tid & 63;
    int wr = wave >> 1, wc = wave & 1;   // wr: j-half of 128-subtile, wc: i-half of 64
    int lane15 = lane & 15, quad = lane >> 4;
    int cid = blockIdx.x, sid = blockIdx.y;
    int i0 = sid * 64, j00 = cid * 256;

    // per-lane row info (2 rows: ni = 0..1)
    float si[2], nR2[2];
    int ci4[2], ig[2];
#pragma unroll
    for (int ni = 0; ni < 2; ++ni) {
        int i = i0 + wc * 32 + ni * 16 + lane15;
        ig[ni] = i;
        si[ni] = sq[i];
        nR2[ni] = -Rrow[i] * LOG2EF;
        ci4[ni] = camid[i];
    }

    float tI[2][LI], tX[2][LX], sIa[2], sXa[2];
#pragma unroll
    for (int ni = 0; ni < 2; ++ni) {
#pragma unroll
        for (int q = 0; q < LI; ++q) tI[ni][q] = -INFINITY;
#pragma unroll
        for (int q = 0; q < LX; ++q) tX[ni][q] = -INFINITY;
        sIa[ni] = 0.0f; sXa[ni] = 0.0f;
    }

    // staging maps: A-side 128 rows x 2 halves (16B each); B-side 64 rows x 4 quarters
    int srowA = tid >> 1, shalf = tid & 1;
    int srowB = tid >> 2, squart = tid & 3;
    const ushort_t* gBh = Fhi + (size_t)(i0 + srowB) * D + squart * 8;
    const ushort_t* gBl = Flo + (size_t)(i0 + srowB) * D + squart * 8;
    ushort_t* sdstAh = ldsAh + srowA * LDST + shalf * 16;
    ushort_t* sdstAl = ldsAl + srowA * LDST + shalf * 16;
    ushort_t* sdstBh = ldsBh + srowB * LDST + squart * 8;
    ushort_t* sdstBl = ldsBl + srowB * LDST + squart * 8;

#pragma unroll 1
    for (int jt = 0; jt < 2; ++jt) {
        int j0 = j00 + jt * 128;
        const ushort_t* gAh = Fhi + (size_t)(j0 + srowA) * D + shalf * 16;
        const ushort_t* gAl = Flo + (size_t)(j0 + srowA) * D + shalf * 16;
        floatx4 acc[4][2] = {};

#pragma unroll 1
        for (int kt = 0; kt < 8; ++kt) {
            int koff = kt * 32;
            short8 ra[2], rb[2], rc, rd;
#pragma unroll
            for (int q = 0; q < 2; ++q) {
                ra[q] = *(const short8*)(gAh + koff + q * 8);
                rb[q] = *(const short8*)(gAl + koff + q * 8);
            }
            rc = *(const short8*)(gBh + koff);
            rd = *(const short8*)(gBl + koff);
            __syncthreads();
#pragma unroll
            for (int q = 0; q < 2; ++q) {
                *(short8*)(sdstAh + q * 8) = ra[q];
                *(short8*)(sdstAl + q * 8) = rb[q];
            }
            *(short8*)(sdstBh) = rc;
            *(short8*)(sdstBl) = rd;
            __syncthreads();

            int eoff = quad * 8;
            short8 ahi[4], alo[4];
#pragma unroll
            for (int mi = 0; mi < 4; ++mi) {
                int r = wr * 64 + mi * 16 + lane15;  // j-side rows [0,128)
                ahi[mi] = *(const short8*)(ldsAh + r * LDST + eoff);
                alo[mi] = *(const short8*)(ldsAl + r * LDST + eoff);
            }
            // B fragments read per-ni to keep peak VGPR under the (256,4) cap
#pragma unroll
            for (int ni = 0; ni < 2; ++ni) {
                int r = wc * 32 + ni * 16 + lane15;  // i-side rows [0,64)
                short8 bhi = *(const short8*)(ldsBh + r * LDST + eoff);
                short8 blo = *(const short8*)(ldsBl + r * LDST + eoff);
#pragma unroll
                for (int mi = 0; mi < 4; ++mi) {
                    acc[mi][ni] = __builtin_amdgcn_mfma_f32_16x16x32_bf16(ahi[mi], bhi, acc[mi][ni], 0, 0, 0);
                    acc[mi][ni] = __builtin_amdgcn_mfma_f32_16x16x32_bf16(ahi[mi], blo, acc[mi][ni], 0, 0, 0);
                    acc[mi][ni] = __builtin_amdgcn_mfma_f32_16x16x32_bf16(alo[mi], bhi, acc[mi][ni], 0, 0, 0);
                }
            }
        }

        // diagonal: i-range [sid*64,+64) meets j-subtile [cid*256+jt*128,+128)
        // iff (sid>>1) == 2*cid + jt
        if (cid == (sid >> 2) && jt == ((sid >> 1) & 1))
            epi_tile<true>(acc, j0, wr, quad, si, nR2, ci4, ig, sq, camid, tI, tX, sIa, sXa);
        else
            epi_tile<false>(acc, j0, wr, quad, si, nR2, ci4, ig, sq, camid, tI, tX, sIa, sXa);
    }

    // merge across the 4 quads sharing each row (butterfly, offsets 16 & 32).
    // CRITICAL: snapshot ALL partner values BEFORE mutating own lists.
#pragma unroll
    for (int off = 16; off <= 32; off <<= 1) {
#pragma unroll
        for (int ni = 0; ni < 2; ++ni) {
            sIa[ni] += __shfl_xor(sIa[ni], off, 64);
            sXa[ni] += __shfl_xor(sXa[ni], off, 64);
            float oI[LI], oX[LX];
#pragma unroll
            for (int q = 0; q < LI; ++q) oI[q] = __shfl_xor(tI[ni][q], off, 64);
#pragma unroll
            for (int q = 0; q < LX; ++q) oX[q] = __shfl_xor(tX[ni][q], off, 64);
#pragma unroll
            for (int q = 0; q < LI; ++q) insert_desc<LI>(tI[ni], oI[q]);
#pragma unroll
            for (int q = 0; q < LX; ++q) insert_desc<LX>(tX[ni], oX[q]);
        }
    }

    if (quad == 0) {
        int p = cid * 2 + wr;
#pragma unroll
        for (int ni = 0; ni < 2; ++ni) {
            size_t idx = (size_t)p * N + ig[ni];
            partA[idx] = make_float4(tI[ni][0], tI[ni][1], tI[ni][2], sIa[ni]);
            partB[idx] = make_float4(tX[ni][0], tX[ni][1], tX[ni][2], tX[ni][3]);
            partC[idx] = make_float4(tX[ni][4], tX[ni][5], sXa[ni], 0.0f);
        }
    }
}

// ---------------- Kernel 3: merge partials -> per-row loss -> global sum ----------------
// Stored list values are BASE-2 keys k2 = (x - R)*log2e; exp contribution is
// exp2(k2) = exp(x - R); natural log re-enters via *LN2 where needed.
// Block-reduces 256 rows and atomicAdds the scaled partial into out[0]
// (zeroed by prep_kernel earlier in the stream) -- removes the final_reduce launch.
__global__ __launch_bounds__(256) void merge_kernel(const float4* __restrict__ partA,
                                                    const float4* __restrict__ partB,
                                                    const float4* __restrict__ partC,
                                                    const float* __restrict__ Rrow,
                                                    float* __restrict__ out) {
    int tid = threadIdx.x;
    int row = blockIdx.x * 256 + tid;
    float mI[LI] = {-INFINITY, -INFINITY, -INFINITY};
    float mX[LX] = {-INFINITY, -INFINITY, -INFINITY, -INFINITY, -INFINITY, -INFINITY};
    float SI = 0.0f, SX = 0.0f;
#pragma unroll 4
    for (int p = 0; p < PPARTS; ++p) {
        size_t idx = (size_t)p * N + row;
        float4 a = partA[idx];
        float4 b = partB[idx];
        float4 c = partC[idx];
        insert_desc<LI>(mI, a.x); insert_desc<LI>(mI, a.y); insert_desc<LI>(mI, a.z);
        SI += a.w;
        insert_desc<LX>(mX, b.x); insert_desc<LX>(mX, b.y);
        insert_desc<LX>(mX, b.z); insert_desc<LX>(mX, b.w);
        insert_desc<LX>(mX, c.x); insert_desc<LX>(mX, c.y);
        SX += c.z;
    }
    float R = Rrow[row];
    // intra: exclude diag (by construction) + top-3 values
    float subI = fast_exp2(mI[0]) + fast_exp2(mI[1]) + fast_exp2(mI[2]);
    float restI = fmaxf(SI - subI, 1e-37f);
    float yI = R + logf(restI);
    float hI = fmaxf(yI + SCALEF * sqrtf(EPSF) + MARGIN_INTRA, 0.0f);  // -x0 = +10*sqrt(eps)
    // inter: exclude top-6; -x0 + yX = logf(restX) - mX[0]*ln2  (R cancels)
    float subX = fast_exp2(mX[0]) + fast_exp2(mX[1]) + fast_exp2(mX[2]) +
                 fast_exp2(mX[3]) + fast_exp2(mX[4]) + fast_exp2(mX[5]);
    float restX = fmaxf(SX - subX, 1e-37f);
    float hX = fmaxf(logf(restX) - mX[0] * LN2F + MARGIN_INTER, 0.0f);
    float l = hI + 0.5f * hX;

    __shared__ float sbuf[256];
    sbuf[tid] = l;
    __syncthreads();
    for (int stride = 128; stride > 0; stride >>= 1) {
        if (tid < stride) sbuf[tid] += sbuf[tid + stride];
        __syncthreads();
    }
    if (tid == 0) atomicAdd(out, sbuf[0] * (1.0f / (float)N));
}

extern "C" void kernel_launch(void* const* d_in, const int* in_sizes, int n_in,
                              void* d_out, int out_size, void* d_ws, size_t ws_size,
                              hipStream_t stream) {
    const float* F = (const float*)d_in[0];
    const int* camid = (const int*)d_in[1];
    float* out = (float*)d_out;
    char* ws = (char*)d_ws;

    ushort_t* Fhi = (ushort_t*)ws;                               // 2 MB
    ushort_t* Flo = Fhi + (size_t)N * D;                         // 2 MB
    float* sq = (float*)(ws + 2 * (size_t)N * D * 2);            // 16 KB
    float* Rrow = sq + N;                                        // 16 KB
    float* rowloss = Rrow + N;                                   // 16 KB (unused, kept for layout)
    (void)rowloss;
    float4* partA = (float4*)(ws + 2 * (size_t)N * D * 2 + 3 * N * 4);  // 2 MB each
    float4* partB = partA + (size_t)PPARTS * N;
    float4* partC = partB + (size_t)PPARTS * N;

    prep_kernel<<<N, 64, 0, stream>>>(F, Fhi, Flo, sq, Rrow, out);
    fused_kernel<<<dim3(NCHUNK, NSTRIP), 256, 0, stream>>>(Fhi, Flo, sq, Rrow, camid,
                                                           partA, partB, partC);
    merge_kernel<<<N / 256, 256, 0, stream>>>(partA, partB, partC, Rrow, out);
}

// Round 4
// 124.965 us; speedup vs baseline: 1.0210x; 1.0210x over previous
//
#include <hip/hip_runtime.h>
#include <hip/hip_bf16.h>
#include <math.h>

#define N 4096
#define D 256
#define SCALEF 10.0f
#define EPSF 1e-5f
#define MARGIN_INTRA 40.0f
#define MARGIN_INTER 6.0f
// reference excludes sorted_intra[0:4] = diagonal + top-3 non-diag, sorted_inter[0:6]
#define LI 3
#define LX 6
#define NCHUNK 16   // j-chunks of 256
#define NSTRIP 64   // i-strips of 64 -> 1024 blocks = 4 blocks/CU
#define PPARTS (NCHUNK * 2)  // partial per (chunk, wr)

#define LOG2EF 1.44269504f
#define LN2F 0.69314718f

typedef unsigned short ushort_t;
typedef __attribute__((ext_vector_type(8))) short short8;
typedef __attribute__((ext_vector_type(4))) float floatx4;

__device__ __forceinline__ ushort_t f2bf(float x) {
    __hip_bfloat16 h = __float2bfloat16(x);
    return *reinterpret_cast<ushort_t*>(&h);
}
__device__ __forceinline__ float bf2f(ushort_t u) {
    __hip_bfloat16 h = *reinterpret_cast<__hip_bfloat16*>(&u);
    return __bfloat162float(h);
}

__device__ __forceinline__ float fast_exp2(float x) {
#if __has_builtin(__builtin_amdgcn_exp2f)
    return __builtin_amdgcn_exp2f(x);
#else
    return exp2f(x);
#endif
}

// Async global->LDS DMA, 16B per lane. LDS dest = wave-uniform base + lane*16
// (lane-linear, NOT per-lane scatter); global src IS per-lane -> swizzled LDS
// layouts are achieved by pre-swizzling the SOURCE address (m173 pattern).
__device__ __forceinline__ void dma16(const void* g, void* l) {
    __builtin_amdgcn_global_load_lds(
        (const __attribute__((address_space(1))) unsigned int*)g,
        (__attribute__((address_space(3))) unsigned int*)l, 16, 0, 0);
}

// Insert v into descending-sorted list t[0..L-1], keep top L.
// t0' = max(t0,v); tq' = med3(t[q-1], t[q], v)  -> L ops, depth-1 chain.
template <int L>
__device__ __forceinline__ void insert_desc(float (&t)[L], float v) {
    float top = fmaxf(t[0], v);
#pragma unroll
    for (int q = L - 1; q >= 1; --q)
        t[q] = __builtin_amdgcn_fmed3f(t[q - 1], t[q], v);
    t[0] = top;
}

// ---------------- Kernel 1: per-row sq, R, bf16 hi/lo split ----------------
__global__ __launch_bounds__(64) void prep_kernel(const float* __restrict__ F,
                                                  ushort_t* __restrict__ Fhi,
                                                  ushort_t* __restrict__ Flo,
                                                  float* __restrict__ sq,
                                                  float* __restrict__ Rrow,
                                                  float* __restrict__ out) {
    int row = blockIdx.x;
    int lane = threadIdx.x;
    if (row == 0 && lane == 0) out[0] = 0.0f;  // for merge_kernel's atomicAdd
    float4 v = ((const float4*)(F + (size_t)row * D))[lane];
    ushort4 h, l;
    h.x = f2bf(v.x); l.x = f2bf(v.x - bf2f(h.x));
    h.y = f2bf(v.y); l.y = f2bf(v.y - bf2f(h.y));
    h.z = f2bf(v.z); l.z = f2bf(v.z - bf2f(h.z));
    h.w = f2bf(v.w); l.w = f2bf(v.w - bf2f(h.w));
    ((ushort4*)(Fhi + (size_t)row * D))[lane] = h;
    ((ushort4*)(Flo + (size_t)row * D))[lane] = l;
    float s = v.x * v.x + v.y * v.y + v.z * v.z + v.w * v.w;
#pragma unroll
    for (int off = 32; off > 0; off >>= 1) s += __shfl_down(s, off, 64);
    if (lane == 0) {
        sq[row] = s;
        Rrow[row] = -SCALEF * sqrtf(2.0f * s);  // per-row exp reference shift
    }
}

// ---------------- Kernel 2: fused GEMM + online masked-topk-LSE ----------------
// Block: 64 rows (i) x 256 cols (j), 256 threads. Gram tile TRANSPOSED:
// MFMA A-operand <- j-features (128-row LDS region), B-operand <- i-features
// (64-row region); each lane's acc holds 2 i-rows (ni) x 16 j-cols per mi.
//
// Staging via global_load_lds (width 16): LDS is LINEAR (row stride 64 B =
// one K-step's 32 bf16). Bank spread comes from an XOR swizzle on the 16B
// granule index: phys granule p at row r holds logical granule p ^ ((r>>1)&3)
// (source-side pre-swizzle; ds_read applies the same involution). 16 lanes of
// a quad-group then hit 8 distinct 16B bank-groups -> 2-way (free, m136).
#define KCH 32   // shorts per row per K-step (64 B)
// LDS regions (shorts): Ah[128*32] @0, Al @4096, Bh[64*32] @8192, Bl @10240
#define AH_OFF 0
#define AL_OFF 4096
#define BH_OFF 8192
#define BL_OFF 10240

// Epilogue for one finished 128(j) x (wave-tile) accumulation.
// Keys are base-2: k2 = (x - R)*log2e = fma(d, -SCALE*log2e, -R*log2e);
// exp contribution is one v_exp_f32: exp2(k2) = exp(x - R).
template <bool HD>
__device__ __forceinline__ void epi_tile(
    const floatx4 (&acc)[4][2], int j0, int wr, int quad,
    const float (&si)[2], const float (&nR2)[2], const int (&ci4)[2], const int (&ig)[2],
    const float* __restrict__ sq, const int* __restrict__ camid,
    float (&tI)[2][LI], float (&tX)[2][LX], float (&sIa)[2], float (&sXa)[2]) {
    const float C1 = -SCALEF * LOG2EF;
#pragma unroll
    for (int mi = 0; mi < 4; ++mi) {
        int jg0 = j0 + wr * 64 + mi * 16 + quad * 4;
        float4 sj4 = *(const float4*)(sq + jg0);
        int4 cj4 = *(const int4*)(camid + jg0);
        const float* sjp = (const float*)&sj4;
        const int* cjp = (const int*)&cj4;
#pragma unroll
        for (int ni = 0; ni < 2; ++ni) {
            int dd = jg0 - ig[ni];  // diagonal at r == -dd
            float sie = si[ni] + EPSF;
#pragma unroll
            for (int r = 0; r < 4; ++r) {
                float d2 = sie + sjp[r] - 2.0f * acc[mi][ni][r];
                float d = sqrtf(fmaxf(d2, 1e-12f));
                float k = fmaf(d, C1, nR2[ni]);  // (x - R) * log2e
                float e = fast_exp2(k);
                bool ii = (cjp[r] == ci4[ni]);
                bool okI = HD ? (ii && ((dd + r) != 0)) : ii;
                sIa[ni] += okI ? e : 0.0f;
                sXa[ni] += ii ? 0.0f : e;
                insert_desc<LI>(tI[ni], okI ? k : -INFINITY);
                insert_desc<LX>(tX[ni], ii ? -INFINITY : k);
            }
        }
    }
}

__global__ __launch_bounds__(256, 4) void fused_kernel(
    const ushort_t* __restrict__ Fhi, const ushort_t* __restrict__ Flo,
    const float* __restrict__ sq, const float* __restrict__ Rrow,
    const int* __restrict__ camid,
    float4* __restrict__ partA, float4* __restrict__ partB, float4* __restrict__ partC) {
    __shared__ ushort_t lds[(128 + 128 + 64 + 64) * KCH];  // 24576 B

    int tid = threadIdx.x;
    int wave = tid >> 6, lane = tid & 63;
    int wr = wave >> 1, wc = wave & 1;   // wr: j-half of 128-subtile, wc: i-half of 64
    int lane15 = lane & 15, quad = lane >> 4;
    int cid = blockIdx.x, sid = blockIdx.y;
    int i0 = sid * 64, j00 = cid * 256;

    // per-lane row info (2 rows: ni = 0..1)
    float si[2], nR2[2];
    int ci4[2], ig[2];
#pragma unroll
    for (int ni = 0; ni < 2; ++ni) {
        int i = i0 + wc * 32 + ni * 16 + lane15;
        ig[ni] = i;
        si[ni] = sq[i];
        nR2[ni] = -Rrow[i] * LOG2EF;
        ci4[ni] = camid[i];
    }

    float tI[2][LI], tX[2][LX], sIa[2], sXa[2];
#pragma unroll
    for (int ni = 0; ni < 2; ++ni) {
#pragma unroll
        for (int q = 0; q < LI; ++q) tI[ni][q] = -INFINITY;
#pragma unroll
        for (int q = 0; q < LX; ++q) tX[ni][q] = -INFINITY;
        sIa[ni] = 0.0f; sXa[ni] = 0.0f;
    }

    // ---- staging descriptors: 24 chunks of 1 KiB (= 16 rows x 64 B), wave w
    // owns chunks {w, w+4, ..., w+20}. Chunk c occupies lds[c*512 .. +512).
    // c 0..7: Ah rows [16c,+16)   c 8..15: Al   c 16..19: Bh   c 20..23: Bl
    // Lane l -> row (l>>2), phys granule (l&3); source granule pre-swizzled:
    // q' = (l&3) ^ ((l>>3)&3)  [== p ^ ((row>>1)&3) since row base % 16 == 0]
    const ushort_t* gsrc[6];
    ushort_t* lb[6];
    {
        int rlo = lane >> 2;
        int qsw = (lane & 3) ^ ((lane >> 3) & 3);
#pragma unroll
        for (int it = 0; it < 6; ++it) {
            int c = wave + 4 * it;
            lb[it] = (ushort_t*)lds + (size_t)c * 512;
            const ushort_t* base;
            int rowg;
            if (c < 16) {  // A-side (j): jt advance added in the loop
                base = (c < 8) ? Fhi : Flo;
                rowg = j00 + (c & 7) * 16 + rlo;
            } else {       // B-side (i)
                base = (c < 20) ? Fhi : Flo;
                rowg = i0 + (c & 3) * 16 + rlo;
            }
            gsrc[it] = base + (size_t)rowg * D + qsw * 8;
        }
    }

    // ds_read granule swizzle: row r = (multiple of 16) + lane15, so
    // (r>>1)&3 == (lane15>>1)&3 -> per-thread constant offset.
    int eswz = (quad ^ ((lane15 >> 1) & 3)) * 8;  // shorts

#pragma unroll 1
    for (int jt = 0; jt < 2; ++jt) {
        int j0 = j00 + jt * 128;
        size_t jadv = (size_t)jt * 128 * D;
        floatx4 acc[4][2] = {};

#pragma unroll 1
        for (int kt = 0; kt < 8; ++kt) {
            int koff = kt * KCH;
            __syncthreads();  // previous step's ds_reads done before DMA overwrites
#pragma unroll
            for (int it = 0; it < 4; ++it)          // A-side (jt-dependent)
                dma16(gsrc[it] + jadv + koff, lb[it]);
#pragma unroll
            for (int it = 4; it < 6; ++it)          // B-side
                dma16(gsrc[it] + koff, lb[it]);
            __syncthreads();  // drains vmcnt(0) -> DMA data visible

            short8 ahi[4], alo[4];
#pragma unroll
            for (int mi = 0; mi < 4; ++mi) {
                int r = wr * 64 + mi * 16 + lane15;  // j-side rows [0,128)
                ahi[mi] = *(const short8*)((ushort_t*)lds + AH_OFF + r * KCH + eswz);
                alo[mi] = *(const short8*)((ushort_t*)lds + AL_OFF + r * KCH + eswz);
            }
            // B fragments read per-ni to keep peak VGPR under the (256,4) cap
#pragma unroll
            for (int ni = 0; ni < 2; ++ni) {
                int r = wc * 32 + ni * 16 + lane15;  // i-side rows [0,64)
                short8 bhi = *(const short8*)((ushort_t*)lds + BH_OFF + r * KCH + eswz);
                short8 blo = *(const short8*)((ushort_t*)lds + BL_OFF + r * KCH + eswz);
#pragma unroll
                for (int mi = 0; mi < 4; ++mi) {
                    acc[mi][ni] = __builtin_amdgcn_mfma_f32_16x16x32_bf16(ahi[mi], bhi, acc[mi][ni], 0, 0, 0);
                    acc[mi][ni] = __builtin_amdgcn_mfma_f32_16x16x32_bf16(ahi[mi], blo, acc[mi][ni], 0, 0, 0);
                    acc[mi][ni] = __builtin_amdgcn_mfma_f32_16x16x32_bf16(alo[mi], bhi, acc[mi][ni], 0, 0, 0);
                }
            }
        }

        // diagonal: i-range [sid*64,+64) meets j-subtile [cid*256+jt*128,+128)
        // iff (sid>>1) == 2*cid + jt
        if (cid == (sid >> 2) && jt == ((sid >> 1) & 1))
            epi_tile<true>(acc, j0, wr, quad, si, nR2, ci4, ig, sq, camid, tI, tX, sIa, sXa);
        else
            epi_tile<false>(acc, j0, wr, quad, si, nR2, ci4, ig, sq, camid, tI, tX, sIa, sXa);
    }

    // merge across the 4 quads sharing each row (butterfly, offsets 16 & 32).
    // CRITICAL: snapshot ALL partner values BEFORE mutating own lists.
#pragma unroll
    for (int off = 16; off <= 32; off <<= 1) {
#pragma unroll
        for (int ni = 0; ni < 2; ++ni) {
            sIa[ni] += __shfl_xor(sIa[ni], off, 64);
            sXa[ni] += __shfl_xor(sXa[ni], off, 64);
            float oI[LI], oX[LX];
#pragma unroll
            for (int q = 0; q < LI; ++q) oI[q] = __shfl_xor(tI[ni][q], off, 64);
#pragma unroll
            for (int q = 0; q < LX; ++q) oX[q] = __shfl_xor(tX[ni][q], off, 64);
#pragma unroll
            for (int q = 0; q < LI; ++q) insert_desc<LI>(tI[ni], oI[q]);
#pragma unroll
            for (int q = 0; q < LX; ++q) insert_desc<LX>(tX[ni], oX[q]);
        }
    }

    if (quad == 0) {
        int p = cid * 2 + wr;
#pragma unroll
        for (int ni = 0; ni < 2; ++ni) {
            size_t idx = (size_t)p * N + ig[ni];
            partA[idx] = make_float4(tI[ni][0], tI[ni][1], tI[ni][2], sIa[ni]);
            partB[idx] = make_float4(tX[ni][0], tX[ni][1], tX[ni][2], tX[ni][3]);
            partC[idx] = make_float4(tX[ni][4], tX[ni][5], sXa[ni], 0.0f);
        }
    }
}

// ---------------- Kernel 3: merge partials -> per-row loss -> global sum ----------------
// Stored list values are BASE-2 keys k2 = (x - R)*log2e; exp contribution is
// exp2(k2) = exp(x - R); natural log re-enters via *LN2 where needed.
// Block-reduces 256 rows and atomicAdds the scaled partial into out[0]
// (zeroed by prep_kernel earlier in the stream).
__global__ __launch_bounds__(256) void merge_kernel(const float4* __restrict__ partA,
                                                    const float4* __restrict__ partB,
                                                    const float4* __restrict__ partC,
                                                    const float* __restrict__ Rrow,
                                                    float* __restrict__ out) {
    int tid = threadIdx.x;
    int row = blockIdx.x * 256 + tid;
    float mI[LI] = {-INFINITY, -INFINITY, -INFINITY};
    float mX[LX] = {-INFINITY, -INFINITY, -INFINITY, -INFINITY, -INFINITY, -INFINITY};
    float SI = 0.0f, SX = 0.0f;
#pragma unroll 4
    for (int p = 0; p < PPARTS; ++p) {
        size_t idx = (size_t)p * N + row;
        float4 a = partA[idx];
        float4 b = partB[idx];
        float4 c = partC[idx];
        insert_desc<LI>(mI, a.x); insert_desc<LI>(mI, a.y); insert_desc<LI>(mI, a.z);
        SI += a.w;
        insert_desc<LX>(mX, b.x); insert_desc<LX>(mX, b.y);
        insert_desc<LX>(mX, b.z); insert_desc<LX>(mX, b.w);
        insert_desc<LX>(mX, c.x); insert_desc<LX>(mX, c.y);
        SX += c.z;
    }
    float R = Rrow[row];
    // intra: exclude diag (by construction) + top-3 values
    float subI = fast_exp2(mI[0]) + fast_exp2(mI[1]) + fast_exp2(mI[2]);
    float restI = fmaxf(SI - subI, 1e-37f);
    float yI = R + logf(restI);
    float hI = fmaxf(yI + SCALEF * sqrtf(EPSF) + MARGIN_INTRA, 0.0f);  // -x0 = +10*sqrt(eps)
    // inter: exclude top-6; -x0 + yX = logf(restX) - mX[0]*ln2  (R cancels)
    float subX = fast_exp2(mX[0]) + fast_exp2(mX[1]) + fast_exp2(mX[2]) +
                 fast_exp2(mX[3]) + fast_exp2(mX[4]) + fast_exp2(mX[5]);
    float restX = fmaxf(SX - subX, 1e-37f);
    float hX = fmaxf(logf(restX) - mX[0] * LN2F + MARGIN_INTER, 0.0f);
    float l = hI + 0.5f * hX;

    __shared__ float sbuf[256];
    sbuf[tid] = l;
    __syncthreads();
    for (int stride = 128; stride > 0; stride >>= 1) {
        if (tid < stride) sbuf[tid] += sbuf[tid + stride];
        __syncthreads();
    }
    if (tid == 0) atomicAdd(out, sbuf[0] * (1.0f / (float)N));
}

extern "C" void kernel_launch(void* const* d_in, const int* in_sizes, int n_in,
                              void* d_out, int out_size, void* d_ws, size_t ws_size,
                              hipStream_t stream) {
    const float* F = (const float*)d_in[0];
    const int* camid = (const int*)d_in[1];
    float* out = (float*)d_out;
    char* ws = (char*)d_ws;

    ushort_t* Fhi = (ushort_t*)ws;                               // 2 MB
    ushort_t* Flo = Fhi + (size_t)N * D;                         // 2 MB
    float* sq = (float*)(ws + 2 * (size_t)N * D * 2);            // 16 KB
    float* Rrow = sq + N;                                        // 16 KB
    float* rowloss = Rrow + N;                                   // 16 KB (unused, kept for layout)
    (void)rowloss;
    float4* partA = (float4*)(ws + 2 * (size_t)N * D * 2 + 3 * N * 4);  // 2 MB each
    float4* partB = partA + (size_t)PPARTS * N;
    float4* partC = partB + (size_t)PPARTS * N;

    prep_kernel<<<N, 64, 0, stream>>>(F, Fhi, Flo, sq, Rrow, out);
    fused_kernel<<<dim3(NCHUNK, NSTRIP), 256, 0, stream>>>(Fhi, Flo, sq, Rrow, camid,
                                                           partA, partB, partC);
    merge_kernel<<<N / 256, 256, 0, stream>>>(partA, partB, partC, Rrow, out);
}